// Round 10
// baseline (1198.244 us; speedup 1.0000x reference)
//
#include <hip/hip_runtime.h>
#include <hip/hip_cooperative_groups.h>
#include <hip/hip_bf16.h>
#include <stdint.h>

#define B_ 4
#define S_ 2048
#define E_ 1024

// Session ledger:
//  R1/R2: 8-phase 256^2 port — correct but slower. PARKED.
//  R3: ANCHOR = 256.5us (cvt ~13, QKV ~76, scores <74, PV <74, gaps ~25-35).
//  R4: PV BN=64 + compact Q/K = 262.1. Reverted.
//  R5: PV split-K=2 = 292.8 (atomicAdd RMW). PV occupancy theory dead.
//  R6/R7: x-convert fused into QKV = NaN, then 95us/145MB FETCH. REJECTED.
//  R8: compact Q/K isolated = 256.7 NULL. Trace: no dispatch > ~77us =>
//    ~25-35us inter-dispatch gap overhead = biggest remaining lever.
//  R9: cooperative mega-kernel: absmax 0.298 == max|ref| => out stayed
//    zero => launch likely REJECTED (return code never checked). Alt
//    hypothesis: cross-XCD L2 writeback missing (threadfence too weak).
//  R10 (this, coop strike 2/2): check launch result + fall back to the
//    R8 4-dispatch path on error (same gemm_core bodies => inherited
//    correctness); __threadfence_system() (full L2 wb+inv) before AND
//    after every grid.sync(); rowsum zeroing covers all 8192 entries.
//    Fail-again => revert to R8 permanently, declare plateau.

typedef __bf16 bf16;
typedef __attribute__((ext_vector_type(8))) __bf16 bf16x8;
typedef __attribute__((ext_vector_type(4))) float f32x4;
typedef __attribute__((ext_vector_type(4))) float float4v;
typedef __attribute__((ext_vector_type(4))) unsigned int uint4v;
typedef __attribute__((ext_vector_type(4))) unsigned short ushort4v;

namespace cg = cooperative_groups;

__device__ inline unsigned short f2bf(float f) {
  union { float f; unsigned int u; } c; c.f = f;
  unsigned int u = c.u;
  unsigned int r = (u + 0x7FFFu + ((u >> 16) & 1u)) >> 16;
  return (unsigned short)r;
}

__device__ inline void load16_to_lds(const void* g, void* l) {
  __builtin_amdgcn_global_load_lds(
      (const __attribute__((address_space(1))) void*)g,
      (__attribute__((address_space(3))) void*)l,
      16, 0, 0);
}

// ---------------------------------------------------------------------------
// gemm_core: the R8-proven 128x128 bt-GEMM K-loop + epilogues.
// C[m][n] = sum_k A[m][k]*B[n][k]; (xt, yt, zb) supplied by caller.
// MODE 6: fused QKV epilogue -> compact Q[8192x1024], K (=Q+NX), V^T.
// MODE 7: scores: exp(acc*scale) bf16 + atomic fp32 row-sums.
// MODE 8: PV: fp32 out, divided by rowsum[row].
// ---------------------------------------------------------------------------
template <int MODE>
static __device__ inline void gemm_core(
    int xt, int yt, int zb,
    const bf16* __restrict__ A, const bf16* __restrict__ B,
    void* __restrict__ Cv,
    const float* __restrict__ bias, const float* __restrict__ bias_b,
    const float* __restrict__ bias_v, unsigned short* __restrict__ VtOut,
    float* __restrict__ rowsum,
    int K, int lda, int ldb, int ldc, long sA, long sB, long sC,
    float scale, bf16* As, bf16* Bs) {
  A += (long)zb * sA;
  B += (long)zb * sB;
  const int tid = threadIdx.x;
  const int wave = tid >> 6;
  const int lane = tid & 63;
  const int lrow = lane & 15;
  const int quad = lane >> 4;
  const int row0 = yt * 128;
  const int col0 = xt * 128;
  const int wm = (wave >> 1) * 64;
  const int wn = (wave & 1) * 64;

  f32x4 acc[4][4] = {};

  // staging geometry: r0 in [0,32), c0 in {0,8,...,56}; rows r0+32i
  const int r0 = wave * 8 + (lane >> 3);
  const int c0 = (lane & 7) * 8;

  const bf16* pA0 = A + (long)(row0 + r0) * lda + c0;
  const bf16* pA1 = pA0 + 32L * lda;
  const bf16* pA2 = pA0 + 64L * lda;
  const bf16* pA3 = pA0 + 96L * lda;
  const bf16* pB0 = B + (long)(col0 + r0) * ldb + c0;
  const bf16* pB1 = pB0 + 32L * ldb;
  const bf16* pB2 = pB0 + 64L * ldb;
  const bf16* pB3 = pB0 + 96L * ldb;
  bf16* ldsA = As + wave * 512;  // wave-uniform; HW scatters lane*16B
  bf16* ldsB = Bs + wave * 512;

  for (int ks = 0; ks < K; ks += 64) {
    load16_to_lds(pA0, ldsA);
    load16_to_lds(pA1, ldsA + 2048);
    load16_to_lds(pA2, ldsA + 4096);
    load16_to_lds(pA3, ldsA + 6144);
    load16_to_lds(pB0, ldsB);
    load16_to_lds(pB1, ldsB + 2048);
    load16_to_lds(pB2, ldsB + 4096);
    load16_to_lds(pB3, ldsB + 6144);
    __syncthreads();
#pragma unroll
    for (int kk = 0; kk < 64; kk += 32) {
      bf16x8 af[4], bfr[4];
#pragma unroll
      for (int i = 0; i < 4; ++i)
        af[i] = *(const bf16x8*)(As + (wm + i * 16 + lrow) * 64 + kk + quad * 8);
#pragma unroll
      for (int j = 0; j < 4; ++j)
        bfr[j] = *(const bf16x8*)(Bs + (wn + j * 16 + lrow) * 64 + kk + quad * 8);
#pragma unroll
      for (int i = 0; i < 4; ++i)
#pragma unroll
        for (int j = 0; j < 4; ++j)
          acc[i][j] = __builtin_amdgcn_mfma_f32_16x16x32_bf16(af[i], bfr[j], acc[i][j], 0, 0, 0);
    }
    __syncthreads();
    pA0 += 64; pA1 += 64; pA2 += 64; pA3 += 64;
    pB0 += 64; pB1 += 64; pB2 += 64; pB3 += 64;
  }

  // epilogue: D mapping (verified): row = quad*4 + r (m), col = lrow (n)
  if constexpr (MODE == 8) {
    float* C = (float*)Cv + (long)zb * sC;
    const float* rs = rowsum + (long)zb * S_;
#pragma unroll
    for (int i = 0; i < 4; ++i) {
#pragma unroll
      for (int r = 0; r < 4; ++r) {
        const int row = row0 + wm + i * 16 + quad * 4 + r;
        const float inv = 1.0f / rs[row];
#pragma unroll
        for (int j = 0; j < 4; ++j) {
          const int col = col0 + wn + j * 16 + lrow;
          C[(long)row * ldc + col] = acc[i][j][r] * inv;
        }
      }
    }
  } else if constexpr (MODE == 7) {
    unsigned short* C = (unsigned short*)Cv + (long)zb * sC;
    float* rs = rowsum + (long)zb * S_;
    float rsump[4][4];
#pragma unroll
    for (int i = 0; i < 4; ++i)
#pragma unroll
      for (int r = 0; r < 4; ++r) rsump[i][r] = 0.f;
#pragma unroll
    for (int j = 0; j < 4; ++j) {
      const int col = col0 + wn + j * 16 + lrow;
#pragma unroll
      for (int i = 0; i < 4; ++i) {
#pragma unroll
        for (int r = 0; r < 4; ++r) {
          const int row = row0 + wm + i * 16 + quad * 4 + r;
          const float e = __expf(acc[i][j][r] * scale);
          rsump[i][r] += e;
          C[(long)row * ldc + col] = f2bf(e);
        }
      }
    }
#pragma unroll
    for (int i = 0; i < 4; ++i) {
#pragma unroll
      for (int r = 0; r < 4; ++r) {
        float v = rsump[i][r];
        v += __shfl_xor(v, 1);
        v += __shfl_xor(v, 2);
        v += __shfl_xor(v, 4);
        v += __shfl_xor(v, 8);
        if (lrow == 0)
          atomicAdd(&rs[row0 + wm + i * 16 + quad * 4 + r], v);
      }
    }
  } else {  // MODE 6: fused QKV. Q, K compact [8192 x 1024] bufs.
    if (col0 < 2 * E_) {
      unsigned short* Cq = (unsigned short*)Cv;              // Q buffer
      unsigned short* Ck = Cq + (long)B_ * S_ * E_;          // K buffer
      unsigned short* C;
      const float* bb;
      int cbase;
      if (col0 < E_) { C = Cq; bb = bias;   cbase = col0; }
      else           { C = Ck; bb = bias_b; cbase = col0 - E_; }
#pragma unroll
      for (int j = 0; j < 4; ++j) {
        const int col = cbase + wn + j * 16 + lrow;
        const float bcol = bb[col];
#pragma unroll
        for (int i = 0; i < 4; ++i) {
#pragma unroll
          for (int r = 0; r < 4; ++r) {
            const int row = row0 + wm + i * 16 + quad * 4 + r;
            C[(long)row * ldc + col] = f2bf(acc[i][j][r] + bcol);
          }
        }
      }
    } else {
      // V block: write transposed. e = col-2048; Vt[e][bs], 4 contiguous bs.
#pragma unroll
      for (int j = 0; j < 4; ++j) {
        const int e = col0 + wn + j * 16 + lrow - 2 * E_;
        const float bv_ = bias_v[e];
#pragma unroll
        for (int i = 0; i < 4; ++i) {
          const int row = row0 + wm + i * 16 + quad * 4;
          ushort4v o;
          o.x = f2bf(acc[i][j][0] + bv_);
          o.y = f2bf(acc[i][j][1] + bv_);
          o.z = f2bf(acc[i][j][2] + bv_);
          o.w = f2bf(acc[i][j][3] + bv_);
          *(ushort4v*)(VtOut + (long)e * (B_ * S_) + row) = o;
        }
      }
    }
  }
}

// ---------------------------------------------------------------------------
// mega: persistent cooperative kernel. Grid 1024 x 256 (4 blocks/CU exact;
// 32KB LDS -> 5/CU cap, VGPR<=128 via launch_bounds -> fits).
// P0 convert+zero | P1 QKV (1536 tiles) | P2 scores (1024) | P3 PV (512).
// __threadfence_system() (L2 writeback + inv, cross-XCD safe) around syncs.
// ---------------------------------------------------------------------------
__global__ __launch_bounds__(256, 4) void mega(
    const float* __restrict__ x, const float* __restrict__ w0,
    const float* __restrict__ w1, const float* __restrict__ w2,
    const float* __restrict__ bq, const float* __restrict__ bk,
    const float* __restrict__ bv, float* __restrict__ out,
    char* __restrict__ ws) {
  __shared__ bf16 As[128 * 64];
  __shared__ bf16 Bs[128 * 64];

  const long NX = (long)B_ * S_ * E_;  // 8388608
  const long NW = (long)E_ * E_;       // 1048576
  bf16* xb  = (bf16*)ws;               // [8192 x 1024]
  bf16* wqb = xb + NX;                 // wqb|wkb|wvb contiguous
  bf16* Qc  = wqb + 3 * NW;            // [8192 x 1024]
  bf16* Kc  = Qc + NX;                 // [8192 x 1024]
  bf16* Vt  = Kc + NX;                 // [1024 x 8192]
  bf16* Sc  = Vt + NX;                 // [4][2048 x 2048]
  float* rowsum = (float*)(Sc + (long)B_ * S_ * S_);  // [4][2048]

  cg::grid_group grid = cg::this_grid();
  const int bid = blockIdx.x;
  const int tid = threadIdx.x;

  // ---- P0: fp32->bf16 convert (x + 3 weights) + rowsum zeroing (8192) ----
  for (int u = bid; u < 11296; u += 1024) {
    if (u >= 11264) {
      rowsum[(u - 11264) * 256 + tid] = 0.f;
      continue;
    }
    const long off = (long)u * 256 + tid;  // float4 units
    const float* in;
    long ibase;
    if (u < 8192)       { in = x;  ibase = 0; }
    else if (u < 9216)  { in = w0; ibase = 8192L * 256; }
    else if (u < 10240) { in = w1; ibase = 9216L * 256; }
    else                { in = w2; ibase = 10240L * 256; }
    float4v f = ((const float4v*)in)[off - ibase];
    ushort4v o;
    o.x = f2bf(f.x); o.y = f2bf(f.y); o.z = f2bf(f.z); o.w = f2bf(f.w);
    ((ushort4v*)xb)[off] = o;
  }
  __threadfence_system();
  grid.sync();
  __threadfence_system();

  // ---- P1: QKV = x @ [Wq;Wk;Wv]^T + bias. 1536 tiles (24 x 64). ----
  for (int t = bid; t < 1536; t += 1024) {
    gemm_core<6>(t % 24, t / 24, 0, xb, wqb, Qc, bq, bk, bv,
                 (unsigned short*)Vt, nullptr,
                 E_, E_, E_, E_, 0, 0, 0, 1.f, As, Bs);
  }
  __threadfence_system();
  grid.sync();
  __threadfence_system();

  // ---- P2: exp-scores + atomic row sums. 1024 tiles, XCD-pinned. ----
  {
    const int xcd = bid & 7;
    const int local = bid >> 3;
    const int zb = xcd >> 1;
    const int w = (xcd & 1) * 128 + local;   // NXT=16, nyt=16
    gemm_core<7>(w % 16, w / 16, zb, Qc, Kc, Sc,
                 nullptr, nullptr, nullptr, nullptr, rowsum,
                 E_, E_, E_, S_,
                 (long)S_ * E_, (long)S_ * E_, (long)S_ * S_, 0.03125f,
                 As, Bs);
  }
  __threadfence_system();
  grid.sync();
  __threadfence_system();

  // ---- P3: out = (P~ @ V) / rowsum. 512 tiles, XCD-pinned. ----
  if (bid < 512) {
    const int xcd = bid & 7;
    const int local = bid >> 3;
    const int zb = xcd >> 1;
    const int w = (xcd & 1) * 64 + local;    // NXT=8, nyt=16
    gemm_core<8>(w % 8, w / 8, zb, Sc, Vt, out,
                 nullptr, nullptr, nullptr, nullptr, rowsum,
                 S_, S_, B_ * S_, E_,
                 (long)S_ * S_, (long)S_, (long)S_ * E_, 1.f,
                 As, Bs);
  }
}

// ---------------------------------------------------------------------------
// Fallback path (R8-proven 4-dispatch): same gemm_core bodies.
// ---------------------------------------------------------------------------
__global__ __launch_bounds__(256) void k_cvt(
    const float* __restrict__ x, const float* __restrict__ w0,
    const float* __restrict__ w1, const float* __restrict__ w2,
    unsigned short* __restrict__ out, float* __restrict__ rowsum) {
  if (blockIdx.x >= 11264) {  // 32 blocks: zero rowsum[8192]
    rowsum[(blockIdx.x - 11264) * 256 + threadIdx.x] = 0.f;
    return;
  }
  const long off = (long)blockIdx.x * 256 + threadIdx.x;
  const float* in;
  long ibase;
  if (blockIdx.x < 8192)       { in = x;  ibase = 0; }
  else if (blockIdx.x < 9216)  { in = w0; ibase = 8192L * 256; }
  else if (blockIdx.x < 10240) { in = w1; ibase = 9216L * 256; }
  else                         { in = w2; ibase = 10240L * 256; }
  float4v f = ((const float4v*)in)[off - ibase];
  ushort4v o;
  o.x = f2bf(f.x); o.y = f2bf(f.y); o.z = f2bf(f.z); o.w = f2bf(f.w);
  ((ushort4v*)out)[off] = o;
}

__global__ __launch_bounds__(256, 4) void k_qkv(
    const bf16* __restrict__ xb, const bf16* __restrict__ wqb,
    bf16* __restrict__ Qc, const float* __restrict__ bq,
    const float* __restrict__ bk, const float* __restrict__ bv,
    unsigned short* __restrict__ Vt) {
  __shared__ bf16 As[128 * 64];
  __shared__ bf16 Bs[128 * 64];
  gemm_core<6>(blockIdx.x, blockIdx.y, 0, xb, wqb, Qc, bq, bk, bv, Vt,
               nullptr, E_, E_, E_, E_, 0, 0, 0, 1.f, As, Bs);
}

__global__ __launch_bounds__(256, 4) void k_sc(
    const bf16* __restrict__ Qc, const bf16* __restrict__ Kc,
    unsigned short* __restrict__ Sc, float* __restrict__ rowsum) {
  __shared__ bf16 As[128 * 64];
  __shared__ bf16 Bs[128 * 64];
  const int xcd = blockIdx.x & 7;
  const int local = blockIdx.x >> 3;
  const int zb = xcd >> 1;
  const int w = (xcd & 1) * 128 + local;   // NXT=16, nyt=16
  gemm_core<7>(w % 16, w / 16, zb, Qc, Kc, (void*)Sc,
               nullptr, nullptr, nullptr, nullptr, rowsum,
               E_, E_, E_, S_,
               (long)S_ * E_, (long)S_ * E_, (long)S_ * S_, 0.03125f, As, Bs);
}

__global__ __launch_bounds__(256, 4) void k_pv(
    const bf16* __restrict__ Sc, const bf16* __restrict__ Vt,
    float* __restrict__ out, float* __restrict__ rowsum) {
  __shared__ bf16 As[128 * 64];
  __shared__ bf16 Bs[128 * 64];
  const int xcd = blockIdx.x & 7;
  const int local = blockIdx.x >> 3;
  const int zb = xcd >> 1;
  const int w = (xcd & 1) * 64 + local;    // NXT=8, nyt=16
  gemm_core<8>(w % 8, w / 8, zb, Sc, Vt, out,
               nullptr, nullptr, nullptr, nullptr, rowsum,
               S_, S_, B_ * S_, E_,
               (long)S_ * S_, (long)S_, (long)S_ * E_, 1.f, As, Bs);
}

// ---------------------------------------------------------------------------
extern "C" void kernel_launch(void* const* d_in, const int* in_sizes, int n_in,
                              void* d_out, int out_size, void* d_ws, size_t ws_size,
                              hipStream_t stream) {
  const float* x    = (const float*)d_in[0];
  const float* wq_w = (const float*)d_in[1];
  const float* wq_b = (const float*)d_in[2];
  const float* wk_w = (const float*)d_in[3];
  const float* wk_b = (const float*)d_in[4];
  const float* wv_w = (const float*)d_in[5];
  const float* wv_b = (const float*)d_in[6];
  float* out = (float*)d_out;
  char* ws = (char*)d_ws;

  const long NX = (long)B_ * S_ * E_;
  const long NW = (long)E_ * E_;
  bf16* xb  = (bf16*)ws;
  bf16* wqb = xb + NX;
  bf16* Qc  = wqb + 3 * NW;
  bf16* Kc  = Qc + NX;
  bf16* Vt  = Kc + NX;
  bf16* Sc  = Vt + NX;
  float* rowsum = (float*)(Sc + (long)B_ * S_ * S_);

  void* args[] = {
      (void*)&x, (void*)&wq_w, (void*)&wk_w, (void*)&wv_w,
      (void*)&wq_b, (void*)&wk_b, (void*)&wv_b,
      (void*)&out, (void*)&ws};
  hipError_t err = hipLaunchCooperativeKernel((const void*)mega, dim3(1024),
                                              dim3(256), args, 0, stream);
  if (err != hipSuccess) {
    (void)hipGetLastError();  // clear sticky error, use proven 4-dispatch path
    k_cvt<<<dim3(11296), 256, 0, stream>>>(
        x, wq_w, wk_w, wv_w, (unsigned short*)xb, rowsum);
    k_qkv<<<dim3(24, 64, 1), dim3(256), 0, stream>>>(
        xb, wqb, Qc, wq_b, wk_b, wv_b, (unsigned short*)Vt);
    k_sc<<<dim3(1024), dim3(256), 0, stream>>>(
        Qc, Kc, (unsigned short*)Sc, rowsum);
    k_pv<<<dim3(512), dim3(256), 0, stream>>>(Sc, Vt, out, rowsum);
  }
}

// Round 11
// 251.552 us; speedup vs baseline: 4.7634x; 4.7634x over previous
//
#include <hip/hip_runtime.h>
#include <hip/hip_bf16.h>
#include <stdint.h>

#define B_ 4
#define S_ 2048
#define E_ 1024

// Session ledger (final):
//  R1/R2: 8-phase 256^2 port — correct but slower (~80us/25% vs 75/28%).
//    Suspected compiler-inserted vmcnt drains; needs disasm. PARKED.
//  R3: ANCHOR = 256.5us (cvt ~13, QKV ~76, scores ~70, PV ~62, gaps ~30).
//  R4: PV BN=64 + compact Q/K = 262.1 (Sc re-read doubled). Reverted.
//  R5: PV split-K=2 = 292.8 (fp32 atomicAdd RMW, 64MB). Reverted.
//  R6/R7: x-cvt fused into QKV A-staging = NaN, then 95us/145MB FETCH
//    (fp32 x re-read per col-tile defeats L2). REJECTED.
//  R8: compact Q/K isolated = 256.7 NULL (stride-aliasing theory dead).
//  R9/R10: cooperative mega-kernel A/B: agent-scope fence = WRONG
//    (cross-XCD L2 stale); system-scope fence = correct but 1130us
//    (FETCH 367MB/WRITE 400MB: per-wave L2 wb+inv round-trips every
//    phase's working set through HBM). Single-kernel fusion's coherence
//    tax > the ~30us of launch gaps it saves. CLOSED.
//  R11 (this): pre-committed revert to the R8-proven 4-dispatch config.
//    This is the session's verified optimum (~256.5us).

typedef __bf16 bf16;
typedef __attribute__((ext_vector_type(8))) __bf16 bf16x8;
typedef __attribute__((ext_vector_type(4))) float f32x4;
typedef __attribute__((ext_vector_type(4))) float float4v;
typedef __attribute__((ext_vector_type(4))) unsigned int uint4v;
typedef __attribute__((ext_vector_type(4))) unsigned short ushort4v;

__device__ inline unsigned short f2bf(float f) {
  union { float f; unsigned int u; } c; c.f = f;
  unsigned int u = c.u;
  unsigned int r = (u + 0x7FFFu + ((u >> 16) & 1u)) >> 16;
  return (unsigned short)r;
}

__device__ inline void load16_to_lds(const void* g, void* l) {
  __builtin_amdgcn_global_load_lds(
      (const __attribute__((address_space(1))) void*)g,
      (__attribute__((address_space(3))) void*)l,
      16, 0, 0);
}

// ---------------------------------------------------------------------------
// gemm_core: proven 128x128 bt-GEMM K-loop + epilogues.
// C[m][n] = sum_k A[m][k]*B[n][k]; (xt, yt, zb) supplied by caller.
// MODE 6: fused QKV epilogue -> compact Q[8192x1024], K (=Q+NX), V^T.
// MODE 7: scores: exp(acc*scale) bf16 + atomic fp32 row-sums.
// MODE 8: PV: fp32 out, divided by rowsum[row].
// ---------------------------------------------------------------------------
template <int MODE>
static __device__ inline void gemm_core(
    int xt, int yt, int zb,
    const bf16* __restrict__ A, const bf16* __restrict__ B,
    void* __restrict__ Cv,
    const float* __restrict__ bias, const float* __restrict__ bias_b,
    const float* __restrict__ bias_v, unsigned short* __restrict__ VtOut,
    float* __restrict__ rowsum,
    int K, int lda, int ldb, int ldc, long sA, long sB, long sC,
    float scale, bf16* As, bf16* Bs) {
  A += (long)zb * sA;
  B += (long)zb * sB;
  const int tid = threadIdx.x;
  const int wave = tid >> 6;
  const int lane = tid & 63;
  const int lrow = lane & 15;
  const int quad = lane >> 4;
  const int row0 = yt * 128;
  const int col0 = xt * 128;
  const int wm = (wave >> 1) * 64;
  const int wn = (wave & 1) * 64;

  f32x4 acc[4][4] = {};

  // staging geometry: r0 in [0,32), c0 in {0,8,...,56}; rows r0+32i
  const int r0 = wave * 8 + (lane >> 3);
  const int c0 = (lane & 7) * 8;

  const bf16* pA0 = A + (long)(row0 + r0) * lda + c0;
  const bf16* pA1 = pA0 + 32L * lda;
  const bf16* pA2 = pA0 + 64L * lda;
  const bf16* pA3 = pA0 + 96L * lda;
  const bf16* pB0 = B + (long)(col0 + r0) * ldb + c0;
  const bf16* pB1 = pB0 + 32L * ldb;
  const bf16* pB2 = pB0 + 64L * ldb;
  const bf16* pB3 = pB0 + 96L * ldb;
  bf16* ldsA = As + wave * 512;  // wave-uniform; HW scatters lane*16B
  bf16* ldsB = Bs + wave * 512;

  for (int ks = 0; ks < K; ks += 64) {
    load16_to_lds(pA0, ldsA);
    load16_to_lds(pA1, ldsA + 2048);
    load16_to_lds(pA2, ldsA + 4096);
    load16_to_lds(pA3, ldsA + 6144);
    load16_to_lds(pB0, ldsB);
    load16_to_lds(pB1, ldsB + 2048);
    load16_to_lds(pB2, ldsB + 4096);
    load16_to_lds(pB3, ldsB + 6144);
    __syncthreads();
#pragma unroll
    for (int kk = 0; kk < 64; kk += 32) {
      bf16x8 af[4], bfr[4];
#pragma unroll
      for (int i = 0; i < 4; ++i)
        af[i] = *(const bf16x8*)(As + (wm + i * 16 + lrow) * 64 + kk + quad * 8);
#pragma unroll
      for (int j = 0; j < 4; ++j)
        bfr[j] = *(const bf16x8*)(Bs + (wn + j * 16 + lrow) * 64 + kk + quad * 8);
#pragma unroll
      for (int i = 0; i < 4; ++i)
#pragma unroll
        for (int j = 0; j < 4; ++j)
          acc[i][j] = __builtin_amdgcn_mfma_f32_16x16x32_bf16(af[i], bfr[j], acc[i][j], 0, 0, 0);
    }
    __syncthreads();
    pA0 += 64; pA1 += 64; pA2 += 64; pA3 += 64;
    pB0 += 64; pB1 += 64; pB2 += 64; pB3 += 64;
  }

  // epilogue: D mapping (verified): row = quad*4 + r (m), col = lrow (n)
  if constexpr (MODE == 8) {
    float* C = (float*)Cv + (long)zb * sC;
    const float* rs = rowsum + (long)zb * S_;
#pragma unroll
    for (int i = 0; i < 4; ++i) {
#pragma unroll
      for (int r = 0; r < 4; ++r) {
        const int row = row0 + wm + i * 16 + quad * 4 + r;
        const float inv = 1.0f / rs[row];
#pragma unroll
        for (int j = 0; j < 4; ++j) {
          const int col = col0 + wn + j * 16 + lrow;
          C[(long)row * ldc + col] = acc[i][j][r] * inv;
        }
      }
    }
  } else if constexpr (MODE == 7) {
    unsigned short* C = (unsigned short*)Cv + (long)zb * sC;
    float* rs = rowsum + (long)zb * S_;
    float rsump[4][4];
#pragma unroll
    for (int i = 0; i < 4; ++i)
#pragma unroll
      for (int r = 0; r < 4; ++r) rsump[i][r] = 0.f;
#pragma unroll
    for (int j = 0; j < 4; ++j) {
      const int col = col0 + wn + j * 16 + lrow;
#pragma unroll
      for (int i = 0; i < 4; ++i) {
#pragma unroll
        for (int r = 0; r < 4; ++r) {
          const int row = row0 + wm + i * 16 + quad * 4 + r;
          const float e = __expf(acc[i][j][r] * scale);
          rsump[i][r] += e;
          C[(long)row * ldc + col] = f2bf(e);
        }
      }
    }
#pragma unroll
    for (int i = 0; i < 4; ++i) {
#pragma unroll
      for (int r = 0; r < 4; ++r) {
        float v = rsump[i][r];
        v += __shfl_xor(v, 1);
        v += __shfl_xor(v, 2);
        v += __shfl_xor(v, 4);
        v += __shfl_xor(v, 8);
        if (lrow == 0)
          atomicAdd(&rs[row0 + wm + i * 16 + quad * 4 + r], v);
      }
    }
  } else {  // MODE 6: fused QKV. Q, K compact [8192 x 1024] bufs.
    if (col0 < 2 * E_) {
      unsigned short* Cq = (unsigned short*)Cv;              // Q buffer
      unsigned short* Ck = Cq + (long)B_ * S_ * E_;          // K buffer
      unsigned short* C;
      const float* bb;
      int cbase;
      if (col0 < E_) { C = Cq; bb = bias;   cbase = col0; }
      else           { C = Ck; bb = bias_b; cbase = col0 - E_; }
#pragma unroll
      for (int j = 0; j < 4; ++j) {
        const int col = cbase + wn + j * 16 + lrow;
        const float bcol = bb[col];
#pragma unroll
        for (int i = 0; i < 4; ++i) {
#pragma unroll
          for (int r = 0; r < 4; ++r) {
            const int row = row0 + wm + i * 16 + quad * 4 + r;
            C[(long)row * ldc + col] = f2bf(acc[i][j][r] + bcol);
          }
        }
      }
    } else {
      // V block: write transposed. e = col-2048; Vt[e][bs], 4 contiguous bs.
#pragma unroll
      for (int j = 0; j < 4; ++j) {
        const int e = col0 + wn + j * 16 + lrow - 2 * E_;
        const float bv_ = bias_v[e];
#pragma unroll
        for (int i = 0; i < 4; ++i) {
          const int row = row0 + wm + i * 16 + quad * 4;
          ushort4v o;
          o.x = f2bf(acc[i][j][0] + bv_);
          o.y = f2bf(acc[i][j][1] + bv_);
          o.z = f2bf(acc[i][j][2] + bv_);
          o.w = f2bf(acc[i][j][3] + bv_);
          *(ushort4v*)(VtOut + (long)e * (B_ * S_) + row) = o;
        }
      }
    }
  }
}

// ---------------------------------------------------------------------------
// 4-dispatch pipeline (R8-proven).
// ---------------------------------------------------------------------------
__global__ __launch_bounds__(256) void k_cvt(
    const float* __restrict__ x, const float* __restrict__ w0,
    const float* __restrict__ w1, const float* __restrict__ w2,
    unsigned short* __restrict__ out, float* __restrict__ rowsum) {
  if (blockIdx.x >= 11264) {  // 32 blocks: zero rowsum[8192]
    rowsum[(blockIdx.x - 11264) * 256 + threadIdx.x] = 0.f;
    return;
  }
  const long off = (long)blockIdx.x * 256 + threadIdx.x;
  const float* in;
  long ibase;
  if (blockIdx.x < 8192)       { in = x;  ibase = 0; }
  else if (blockIdx.x < 9216)  { in = w0; ibase = 8192L * 256; }
  else if (blockIdx.x < 10240) { in = w1; ibase = 9216L * 256; }
  else                         { in = w2; ibase = 10240L * 256; }
  float4v f = ((const float4v*)in)[off - ibase];
  ushort4v o;
  o.x = f2bf(f.x); o.y = f2bf(f.y); o.z = f2bf(f.z); o.w = f2bf(f.w);
  ((ushort4v*)out)[off] = o;
}

__global__ __launch_bounds__(256, 4) void k_qkv(
    const bf16* __restrict__ xb, const bf16* __restrict__ wqb,
    bf16* __restrict__ Qc, const float* __restrict__ bq,
    const float* __restrict__ bk, const float* __restrict__ bv,
    unsigned short* __restrict__ Vt) {
  __shared__ bf16 As[128 * 64];
  __shared__ bf16 Bs[128 * 64];
  gemm_core<6>(blockIdx.x, blockIdx.y, 0, xb, wqb, Qc, bq, bk, bv, Vt,
               nullptr, E_, E_, E_, E_, 0, 0, 0, 1.f, As, Bs);
}

__global__ __launch_bounds__(256, 4) void k_sc(
    const bf16* __restrict__ Qc, const bf16* __restrict__ Kc,
    unsigned short* __restrict__ Sc, float* __restrict__ rowsum) {
  __shared__ bf16 As[128 * 64];
  __shared__ bf16 Bs[128 * 64];
  const int xcd = blockIdx.x & 7;
  const int local = blockIdx.x >> 3;
  const int zb = xcd >> 1;
  const int w = (xcd & 1) * 128 + local;   // NXT=16, nyt=16
  gemm_core<7>(w % 16, w / 16, zb, Qc, Kc, (void*)Sc,
               nullptr, nullptr, nullptr, nullptr, rowsum,
               E_, E_, E_, S_,
               (long)S_ * E_, (long)S_ * E_, (long)S_ * S_, 0.03125f, As, Bs);
}

__global__ __launch_bounds__(256, 4) void k_pv(
    const bf16* __restrict__ Sc, const bf16* __restrict__ Vt,
    float* __restrict__ out, float* __restrict__ rowsum) {
  __shared__ bf16 As[128 * 64];
  __shared__ bf16 Bs[128 * 64];
  const int xcd = blockIdx.x & 7;
  const int local = blockIdx.x >> 3;
  const int zb = xcd >> 1;
  const int w = (xcd & 1) * 64 + local;    // NXT=8, nyt=16
  gemm_core<8>(w % 8, w / 8, zb, Sc, Vt, out,
               nullptr, nullptr, nullptr, nullptr, rowsum,
               S_, S_, B_ * S_, E_,
               (long)S_ * S_, (long)S_, (long)S_ * E_, 1.f, As, Bs);
}

// ---------------------------------------------------------------------------
extern "C" void kernel_launch(void* const* d_in, const int* in_sizes, int n_in,
                              void* d_out, int out_size, void* d_ws, size_t ws_size,
                              hipStream_t stream) {
  const float* x    = (const float*)d_in[0];
  const float* wq_w = (const float*)d_in[1];
  const float* wq_b = (const float*)d_in[2];
  const float* wk_w = (const float*)d_in[3];
  const float* wk_b = (const float*)d_in[4];
  const float* wv_w = (const float*)d_in[5];
  const float* wv_b = (const float*)d_in[6];
  float* out = (float*)d_out;
  char* ws = (char*)d_ws;

  const long NX = (long)B_ * S_ * E_;  // 8388608
  const long NW = (long)E_ * E_;       // 1048576
  bf16* xb  = (bf16*)ws;               // [8192 x 1024]
  bf16* wqb = xb + NX;                 // wqb|wkb|wvb contiguous
  bf16* Qc  = wqb + 3 * NW;            // [8192 x 1024] Q compact
  bf16* Kc  = Qc + NX;                 // [8192 x 1024] K compact
  bf16* Vt  = Kc + NX;                 // [1024 x 8192] V transposed
  bf16* Sc  = Vt + NX;                 // [4][2048 x 2048] exp-scores
  float* rowsum = (float*)(Sc + (long)B_ * S_ * S_);  // [4][2048]

  // P0: fp32->bf16 convert (x + 3 weights) + rowsum zeroing
  k_cvt<<<dim3(11296), 256, 0, stream>>>(
      x, wq_w, wk_w, wv_w, (unsigned short*)xb, rowsum);
  // P1: QKV = x @ [Wq;Wk;Wv]^T + bias -> Qc, Kc, Vt
  k_qkv<<<dim3(24, 64, 1), dim3(256), 0, stream>>>(
      xb, wqb, Qc, wq_b, wk_b, wv_b, (unsigned short*)Vt);
  // P2: exp-scores + atomic row sums (XCD-pinned batches)
  k_sc<<<dim3(1024), dim3(256), 0, stream>>>(
      Qc, Kc, (unsigned short*)Sc, rowsum);
  // P3: out = (P~ @ V) / rowsum (XCD-pinned batches)
  k_pv<<<dim3(512), dim3(256), 0, stream>>>(Sc, Vt, out, rowsum);
}